// Round 11
// baseline (1110.018 us; speedup 1.0000x reference)
//
#include <hip/hip_runtime.h>

#define N_NODES 50000
#define N_EDGES 250000
#define DIM 300
#define DIM2 600
#define NL 5
#define MPAD 50048      // 391 * 128
#define KP1 320         // DIM padded to mult of 32
#define KP2 608         // DIM2 padded to mult of 32
#define NP1 640         // DIM2 padded to mult of 128
#define NP2 384         // DIM padded to mult of 128
#define SCAN_BLOCKS 196 // ceil(N_NODES / 256)
#define CT_STRIDE 136   // 128 + 8 pad: breaks epilogue LDS write conflicts

typedef __attribute__((ext_vector_type(8))) _Float16 half8;
typedef __attribute__((ext_vector_type(2))) _Float16 half2v;
typedef __attribute__((ext_vector_type(8))) short short8;
typedef __attribute__((ext_vector_type(4))) float f32x4;
typedef unsigned short ushort;
typedef unsigned int uint;

#define AS1 __attribute__((address_space(1)))
#define AS3 __attribute__((address_space(3)))

// raw barrier with compiler memory fences: does NOT force a vmcnt drain
#define BARRIER() do { \
    asm volatile("" ::: "memory"); \
    __builtin_amdgcn_s_barrier(); \
    asm volatile("" ::: "memory"); \
} while (0)

static __device__ __forceinline__ ushort f2h(float f) {
    _Float16 h = (_Float16)f;
    return __builtin_bit_cast(ushort, h);
}
static __device__ __forceinline__ float h2f(ushort s) {
    return (float)__builtin_bit_cast(_Float16, s);
}
static __device__ __forceinline__ uint pk2(float a, float b) {
    return (uint)f2h(a) | ((uint)f2h(b) << 16);
}
static __device__ __forceinline__ half2v u2h2(uint u) {
    return __builtin_bit_cast(half2v, u);
}

// bijective XCD-contiguous remap (m204)
static __device__ __forceinline__ int xcd_swizzle(int o, int nwg) {
    int q = nwg >> 3, r = nwg & 7;
    int xcd = o & 7, idx = o >> 3;
    return (xcd < r ? xcd * (q + 1) : r * (q + 1) + (xcd - r) * q) + idx;
}

// ---------------- Atom encoder -> h fp16 ----------------
__global__ void atom_enc(const int* __restrict__ x, const float* __restrict__ emb,
                         ushort* __restrict__ h) {
    int idx = blockIdx.x * blockDim.x + threadIdx.x;  // pair index
    const int PAIRS = DIM / 2;  // 150
    if (idx >= N_NODES * PAIRS) return;
    int n = idx / PAIRS, p = idx - n * PAIRS;
    const int* xr = x + n * 9;
    float s0 = 0.f, s1 = 0.f;
#pragma unroll
    for (int i = 0; i < 9; i++) {
        const float2 v = *(const float2*)(emb + (size_t)(i * 128 + xr[i]) * DIM + 2 * p);
        s0 += v.x; s1 += v.y;
    }
    ((uint*)h)[idx] = pk2(s0, s1);
}

// ---------------- CSR build (once per launch; edge_index is layer-invariant) ----------
__global__ void deg_count(const int* __restrict__ ei, int* __restrict__ deg) {
    int e = blockIdx.x * blockDim.x + threadIdx.x;
    if (e < N_EDGES) atomicAdd(&deg[ei[N_EDGES + e]], 1);
}

__global__ void block_sums(const int* __restrict__ deg, int* __restrict__ bsum) {
    __shared__ int red[256];
    int tid = threadIdx.x;
    int node = blockIdx.x * 256 + tid;
    red[tid] = (node < N_NODES) ? deg[node] : 0;
    __syncthreads();
    for (int off = 128; off > 0; off >>= 1) {
        if (tid < off) red[tid] += red[tid + off];
        __syncthreads();
    }
    if (tid == 0) bsum[blockIdx.x] = red[0];
}

__global__ void scan_bsums(int* __restrict__ bsum) {
    __shared__ int s[256];
    int tid = threadIdx.x;
    int orig = (tid < SCAN_BLOCKS) ? bsum[tid] : 0;
    s[tid] = orig;
    __syncthreads();
    for (int off = 1; off < 256; off <<= 1) {
        int v = (tid >= off) ? s[tid - off] : 0;
        __syncthreads();
        s[tid] += v;
        __syncthreads();
    }
    if (tid < SCAN_BLOCKS) bsum[tid] = s[tid] - orig;  // exclusive
}

__global__ void write_rowstart(const int* __restrict__ deg, const int* __restrict__ bsum,
                               int* __restrict__ rowstart, int* __restrict__ cursor) {
    __shared__ int s[256];
    int tid = threadIdx.x;
    int node = blockIdx.x * 256 + tid;
    int d = (node < N_NODES) ? deg[node] : 0;
    s[tid] = d;
    __syncthreads();
    for (int off = 1; off < 256; off <<= 1) {
        int v = (tid >= off) ? s[tid - off] : 0;
        __syncthreads();
        s[tid] += v;
        __syncthreads();
    }
    int excl = s[tid] - d + bsum[blockIdx.x];
    if (node < N_NODES) {
        rowstart[node] = excl;
        cursor[node] = excl;
    }
    if (blockIdx.x == 0 && tid == 0) rowstart[N_NODES] = N_EDGES;
}

// fill CSR with pre-packed edge payload: (src, a0|a1<<8|a2<<16)
__global__ void csr_fill(const int* __restrict__ ei, const int* __restrict__ ea,
                         int* __restrict__ cursor, int2* __restrict__ epack) {
    int e = blockIdx.x * blockDim.x + threadIdx.x;
    if (e < N_EDGES) {
        int d = ei[N_EDGES + e];
        int slot = atomicAdd(&cursor[d], 1);
        int attr = ea[3 * e] | (ea[3 * e + 1] << 8) | (ea[3 * e + 2] << 16);
        epack[slot] = make_int2(ei[e], attr);
    }
}

// -------- fused per-layer: bond table fp32->fp16 + W1 transpose (indep of stats) ------
__global__ void bond_wt(const float* __restrict__ bond, ushort* __restrict__ bondh,
                        const float* __restrict__ W, ushort* __restrict__ Wt) {
    int idx = blockIdx.x * blockDim.x + threadIdx.x;
    const int NB = 48 * (DIM / 2);  // 7200 pair elems
    if (idx < NB) {
        float2 v = *(const float2*)(bond + 2 * idx);
        ((uint*)bondh)[idx] = pk2(v.x, v.y);
        return;
    }
    idx -= NB;
    if (idx >= KP1 * NP1) return;
    int k = idx / NP1, n = idx - k * NP1;
    ushort v = 0;
    if (k < DIM && n < DIM2) v = f2h(W[(size_t)k * DIM2 + n]);
    Wt[(size_t)n * KP1 + k] = v;
}

// -------- pre-transform h once per layer: ht = relu(bn2(h)) with inline stats ---------
// Eliminates the degree-x redundant BN2+ReLU in agg_combine's edge loop.
__global__ void bn_relu_h(const ushort* __restrict__ h, const float* __restrict__ sum2,
                          const float* __restrict__ sq2, const float* __restrict__ g,
                          const float* __restrict__ b, ushort* __restrict__ ht) {
    int idx = blockIdx.x * blockDim.x + threadIdx.x;  // pair index
    const int PAIRS = DIM / 2;
    if (idx >= N_NODES * PAIRS) return;
    int p = idx % PAIRS;
    const float invN = 1.0f / (float)N_NODES;
    float2 s = *(const float2*)(sum2 + 2 * p);
    float2 q = *(const float2*)(sq2 + 2 * p);
    float2 gv = *(const float2*)(g + 2 * p);
    float2 bv = *(const float2*)(b + 2 * p);
    float m0 = s.x * invN, m1 = s.y * invN;
    float sc0 = gv.x * rsqrtf(q.x * invN - m0 * m0 + 1e-5f);
    float sc1 = gv.y * rsqrtf(q.y * invN - m1 * m1 + 1e-5f);
    float sh0 = bv.x - m0 * sc0, sh1 = bv.y - m1 * sc1;
    uint u = ((const uint*)h)[idx];
    float v0 = fmaxf(h2f((ushort)(u & 0xffffu)) * sc0 + sh0, 0.f);
    float v1 = fmaxf(h2f((ushort)(u >> 16)) * sc1 + sh1, 0.f);
    ((uint*)ht)[idx] = pk2(v0, v1);
}

// ------- gather-aggregate + GIN combine on PRE-TRANSFORMED ht + fp16 cast -------------
// Edge chain is now: load ht[src] -> +3 bond adds -> max -> acc (no per-edge BN).
__launch_bounds__(256)
__global__ void agg_combine(const int* __restrict__ rowstart, const int2* __restrict__ epack,
                            const ushort* __restrict__ bondh, const ushort* __restrict__ ht,
                            const float* __restrict__ epsp, int layer,
                            ushort* __restrict__ A1) {
    int node = blockIdx.x * 4 + (threadIdx.x >> 6);
    int lane = threadIdx.x & 63;
    if (node >= MPAD) return;
    uint* row32 = (uint*)(A1 + (size_t)node * KP1);
    if (node >= N_NODES) {
        for (int i = lane; i < KP1 / 2; i += 64) row32[i] = 0;
        return;
    }
    const int PAIRS = DIM / 2;  // 150
    float epsv = 1.0f + epsp[layer];
    const uint* hd = (const uint*)(ht + (size_t)node * DIM);
    float ax[3], ay[3];
#pragma unroll
    for (int i = 0; i < 3; i++) {
        int p = lane + 64 * i;
        ax[i] = 0.f; ay[i] = 0.f;
        if (p < PAIRS) {
            uint u = hd[p];
            ax[i] = epsv * h2f((ushort)(u & 0xffffu));
            ay[i] = epsv * h2f((ushort)(u >> 16));
        }
    }

    auto edge_contrib = [&](int2 pk) {
        const uint* hs = (const uint*)(ht + (size_t)pk.x * DIM);
        int a0 = pk.y & 0xff, a1v = (pk.y >> 8) & 0xff, a2 = (pk.y >> 16) & 0xff;
        const uint* t0 = (const uint*)(bondh + a0 * DIM);
        const uint* t1 = (const uint*)(bondh + (16 + a1v) * DIM);
        const uint* t2 = (const uint*)(bondh + (32 + a2) * DIM);
        const half2v z = {};
#pragma unroll
        for (int i = 0; i < 3; i++) {
            int p = lane + 64 * i;
            if (p < PAIRS) {
                half2v m = u2h2(hs[p]) + u2h2(t0[p]) + u2h2(t1[p]) + u2h2(t2[p]);
                m = __builtin_elementwise_max(m, z);
                ax[i] += (float)m.x;
                ay[i] += (float)m.y;
            }
        }
    };

    int e0 = rowstart[node], e1 = rowstart[node + 1];
    int t = e0;
    for (; t + 1 < e1; t += 2) {
        int2 p0 = epack[t];
        int2 p1 = epack[t + 1];
        edge_contrib(p0);
        edge_contrib(p1);
    }
    if (t < e1) edge_contrib(epack[t]);

#pragma unroll
    for (int i = 0; i < 3; i++) {
        int p = lane + 64 * i;
        if (p < KP1 / 2) row32[p] = (p < PAIRS) ? pk2(ax[i], ay[i]) : 0u;
    }
}

// ------- W2 transpose with BN1 scale computed inline from stats; also emits t1h -------
__global__ void wt_conv2_bn1(const float* __restrict__ W, const float* __restrict__ sum1,
                             const float* __restrict__ sq1, const float* __restrict__ g1v,
                             const float* __restrict__ be1v, ushort* __restrict__ Wt,
                             ushort* __restrict__ th) {
    int idx = blockIdx.x * blockDim.x + threadIdx.x;
    const float invN = 1.0f / (float)N_NODES;
    if (idx < KP2) {  // t1h = shift1/scale1, zero pad past DIM2
        ushort tv = 0;
        if (idx < DIM2) {
            float mean = sum1[idx] * invN;
            float var = sq1[idx] * invN - mean * mean;
            float sc = g1v[idx] * rsqrtf(var + 1e-5f);
            tv = f2h(be1v[idx] / sc - mean);
        }
        th[idx] = tv;
    }
    if (idx >= KP2 * NP2) return;
    int k = idx / NP2, n = idx - k * NP2;
    ushort v = 0;
    if (k < DIM2 && n < DIM) {
        float mean = sum1[k] * invN;
        float var = sq1[k] * invN - mean * mean;
        float sc = g1v[k] * rsqrtf(var + 1e-5f);
        v = f2h(sc * W[(size_t)k * DIM + n]);
    }
    Wt[(size_t)n * KP2 + k] = v;
}

// ---------------- GEMM1: yh = A1 @ Wt1^T + b1, fp16 out + BN stats --------------------
// R4's proven K-loop: depth-2 counted-vmcnt pipeline, 2 buffers, stage(t+2) AFTER the
// fragment-read fence + barrier. Writes yh with stride KP2=608 incl. zero pad cols.
__launch_bounds__(256, 4)
__global__ void gemm_mfma(const ushort* __restrict__ A, const ushort* __restrict__ Wt,
                          const float* __restrict__ bias, ushort* __restrict__ Cout,
                          int M, int KP, int Nc, int strideC, int ntiles,
                          float* __restrict__ csum, float* __restrict__ csq) {
    __shared__ ushort smem[16384];  // 32 KB: As0@0 Bs0@4096 As1@8192 Bs1@12288 (elem offs)
    __shared__ float s_sum[128], s_sq[128];

    int tid = threadIdx.x;
    int w = tid >> 6, lane = tid & 63;
    int quad = lane >> 4, lr = lane & 15;
    int wm = w >> 1, wn = w & 1;
    int wg = xcd_swizzle(blockIdx.x, gridDim.x);
    int m0 = (wg / ntiles) * 128;
    int n0 = (wg % ntiles) * 128;

    if (tid < 128) { s_sum[tid] = 0.f; s_sq[tid] = 0.f; }

    const int kchunk = ((lane & 3) ^ ((lane >> 3) & 3)) * 8;
    const int grow = lane >> 2;
    const ushort* Abase = A + (size_t)m0 * KP + kchunk;
    const ushort* Bbase = Wt + (size_t)n0 * KP + kchunk;
    const int xq = (quad ^ ((lr >> 1) & 3)) * 8;  // matching swizzled read slot

    auto stage = [&](int k0, int buf) {  // 4 glds per wave (2 A + 2 B)
        ushort* dA = smem + buf * 8192;
#pragma unroll
        for (int c = w; c < 8; c += 4)
            __builtin_amdgcn_global_load_lds((const AS1 void*)(Abase + (size_t)(16 * c + grow) * KP + k0),
                                             (AS3 void*)(dA + c * 512), 16, 0, 0);
#pragma unroll
        for (int c = w; c < 8; c += 4)
            __builtin_amdgcn_global_load_lds((const AS1 void*)(Bbase + (size_t)(16 * c + grow) * KP + k0),
                                             (AS3 void*)(dA + 4096 + c * 512), 16, 0, 0);
    };

    f32x4 acc[4][4] = {};
    const int nk = KP >> 5;  // 10

    stage(0, 0);
    stage(32, 1);
    asm volatile("s_waitcnt vmcnt(4)" ::: "memory");  // tile 0 landed; tile 1 in flight
    BARRIER();

    for (int t = 0; t < nk; ++t) {
        const ushort* As = smem + (t & 1) * 8192;
        const ushort* Bs = As + 4096;
        half8 a[4], b[4];
#pragma unroll
        for (int mf = 0; mf < 4; mf++)
            a[mf] = __builtin_bit_cast(half8, *(const short8*)(As + (64 * wm + 16 * mf + lr) * 32 + xq));
#pragma unroll
        for (int nf = 0; nf < 4; nf++)
            b[nf] = __builtin_bit_cast(half8, *(const short8*)(Bs + (64 * wn + 16 * nf + lr) * 32 + xq));
        asm volatile("s_waitcnt lgkmcnt(0)" ::: "memory");  // reads complete -> buf free
        BARRIER();

        if (t + 2 < nk) stage((t + 2) << 5, t & 1);  // overwrite just-freed buffer

        __builtin_amdgcn_s_setprio(1);
#pragma unroll
        for (int mf = 0; mf < 4; mf++)
#pragma unroll
            for (int nf = 0; nf < 4; nf++)
                acc[mf][nf] = __builtin_amdgcn_mfma_f32_16x16x32_f16(a[mf], b[nf], acc[mf][nf], 0, 0, 0);
        __builtin_amdgcn_s_setprio(0);

        if (t + 2 < nk)       { asm volatile("s_waitcnt vmcnt(4)" ::: "memory"); }  // t+1 landed
        else if (t + 1 < nk)  { asm volatile("s_waitcnt vmcnt(0)" ::: "memory"); }  // tail drain
        BARRIER();
    }

    // Epilogue: stats from regs + two 64-row half-tiles through LDS (reuses staging smem)
#pragma unroll
    for (int half = 0; half < 2; half++) {
        if (wm == half) {
#pragma unroll
            for (int nf = 0; nf < 4; nf++) {
                int lcol = 64 * wn + 16 * nf + lr;
                int gn = n0 + lcol;
                float bv = (gn < Nc) ? bias[gn] : 0.f;
                float ps = 0.f, pq = 0.f;
#pragma unroll
                for (int mf = 0; mf < 4; mf++) {
#pragma unroll
                    for (int r = 0; r < 4; r++) {
                        int lrow = 16 * mf + quad * 4 + r;  // 0..63 within half
                        float v = acc[mf][nf][r] + bv;
                        smem[lrow * CT_STRIDE + lcol] = f2h(v);
                        if (m0 + 64 * half + lrow < M && gn < Nc) { ps += v; pq += v * v; }
                    }
                }
                if (gn < Nc) {
                    atomicAdd(&s_sum[lcol], ps);
                    atomicAdd(&s_sq[lcol], pq);
                }
            }
        }
        __syncthreads();
        // coalesced readback: 64 rows x 16 chunks of 8 fp16 (16B); also writes the
        // zero pad cols 600..607 (acc there is 0: Wt1 rows 600..639 zero, bias masked)
#pragma unroll
        for (int it = 0; it < 4; it++) {
            int idx = tid + it * 256;
            int row = idx >> 4, ch = idx & 15;
            int gcol = n0 + ch * 8;
            if (gcol < strideC) {
                *(short8*)(Cout + (size_t)(m0 + 64 * half + row) * strideC + gcol) =
                    *(const short8*)(smem + row * CT_STRIDE + ch * 8);
            }
        }
        __syncthreads();
    }

    if (tid < 128) {
        int gn = n0 + tid;
        if (gn < Nc) {
            atomicAdd(&csum[gn], s_sum[tid]);
            atomicAdd(&csq[gn], s_sq[tid]);
        }
    }
}

// ------- GEMM2: h = max(yh + t1h, 0) @ Wt2^T + b2 -- transform ON THE FRAGMENT --------
// R7/R10 structure (measured 68.8 floor): 3-buf, 1 barrier/step, counted vmcnt.
__launch_bounds__(256)
__global__ void gemm2_fused(const ushort* __restrict__ yh, const ushort* __restrict__ Wt,
                            const ushort* __restrict__ t1h, const float* __restrict__ bias,
                            ushort* __restrict__ hout,
                            float* __restrict__ csum, float* __restrict__ csq) {
    __shared__ ushort smem[24576];
    __shared__ ushort s_t[KP2];
    __shared__ float s_sum[128], s_sq[128];

    int tid = threadIdx.x;
    int w = tid >> 6, lane = tid & 63;
    int quad = lane >> 4, lr = lane & 15;
    int wm = w >> 1, wn = w & 1;
    int wg = xcd_swizzle(blockIdx.x, gridDim.x);
    int m0 = (wg / 3) * 128;
    int n0 = (wg % 3) * 128;

    if (tid < 128) { s_sum[tid] = 0.f; s_sq[tid] = 0.f; }

    const int kchunk = ((lane & 3) ^ ((lane >> 3) & 3)) * 8;
    const int grow = lane >> 2;
    const ushort* Abase = yh + (size_t)m0 * KP2 + kchunk;
    const ushort* Bbase = Wt + (size_t)n0 * KP2 + kchunk;
    const int xq = (quad ^ ((lr >> 1) & 3)) * 8;

    auto stage = [&](int k0, int buf) {  // 4 glds per wave (2 A + 2 B)
        ushort* dA = smem + buf * 4096;
        ushort* dB = smem + 12288 + buf * 4096;
#pragma unroll
        for (int c = w; c < 8; c += 4)
            __builtin_amdgcn_global_load_lds((const AS1 void*)(Abase + (size_t)(16 * c + grow) * KP2 + k0),
                                             (AS3 void*)(dA + c * 512), 16, 0, 0);
#pragma unroll
        for (int c = w; c < 8; c += 4)
            __builtin_amdgcn_global_load_lds((const AS1 void*)(Bbase + (size_t)(16 * c + grow) * KP2 + k0),
                                             (AS3 void*)(dB + c * 512), 16, 0, 0);
    };

    // prologue: s_t (t1h, zero-padded to KP2), then tiles 0,1
    for (int i = tid; i < KP2 / 2; i += 256) ((uint*)s_t)[i] = ((const uint*)t1h)[i];
    asm volatile("s_waitcnt vmcnt(0) lgkmcnt(0)" ::: "memory");  // drain before counting
    stage(0, 0);
    stage(32, 1);
    asm volatile("s_waitcnt vmcnt(4)" ::: "memory");  // tile 0 landed (this wave)
    BARRIER();                                        // all waves; s_t visible

    f32x4 acc[4][4] = {};
    const int nk = KP2 >> 5;  // 19

    int cur = 0;
    for (int t = 0; t < nk; ++t) {
        int s2 = cur + 2; if (s2 >= 3) s2 -= 3;
        if (t + 2 < nk) stage((t + 2) << 5, s2);

        const ushort* As = smem + cur * 4096;
        const ushort* Bs = smem + 12288 + cur * 4096;
        half8 a[4], b[4];
        half8 t8 = *(const half8*)(s_t + (t << 5) + quad * 8);  // broadcast within quad
#pragma unroll
        for (int mf = 0; mf < 4; mf++)
            a[mf] = __builtin_bit_cast(half8, *(const short8*)(As + (64 * wm + 16 * mf + lr) * 32 + xq));
#pragma unroll
        for (int nf = 0; nf < 4; nf++)
            b[nf] = __builtin_bit_cast(half8, *(const short8*)(Bs + (64 * wn + 16 * nf + lr) * 32 + xq));
        asm volatile("s_waitcnt lgkmcnt(0)" ::: "memory");

        __builtin_amdgcn_s_setprio(1);
        {
            half8 z = {};
#pragma unroll
            for (int mf = 0; mf < 4; mf++)
                a[mf] = __builtin_elementwise_max(a[mf] + t8, z);  // BN1 bias + ReLU
        }
#pragma unroll
        for (int mf = 0; mf < 4; mf++)
#pragma unroll
            for (int nf = 0; nf < 4; nf++)
                acc[mf][nf] = __builtin_amdgcn_mfma_f32_16x16x32_f16(a[mf], b[nf], acc[mf][nf], 0, 0, 0);
        __builtin_amdgcn_s_setprio(0);

        if (t + 2 < nk)       { asm volatile("s_waitcnt vmcnt(4)" ::: "memory"); }
        else if (t + 1 < nk)  { asm volatile("s_waitcnt vmcnt(0)" ::: "memory"); }
        BARRIER();

        cur = (cur + 1 == 3) ? 0 : cur + 1;
    }

    // Epilogue: stats from regs + two 64-row half-tiles through LDS
#pragma unroll
    for (int half = 0; half < 2; half++) {
        if (wm == half) {
#pragma unroll
            for (int nf = 0; nf < 4; nf++) {
                int lcol = 64 * wn + 16 * nf + lr;
                int gn = n0 + lcol;
                float bv = (gn < DIM) ? bias[gn] : 0.f;
                float ps = 0.f, pq = 0.f;
#pragma unroll
                for (int mf = 0; mf < 4; mf++) {
#pragma unroll
                    for (int r = 0; r < 4; r++) {
                        int lrow = 16 * mf + quad * 4 + r;  // 0..63 within half
                        float v = acc[mf][nf][r] + bv;
                        smem[lrow * CT_STRIDE + lcol] = f2h(v);
                        if (m0 + 64 * half + lrow < N_NODES && gn < DIM) { ps += v; pq += v * v; }
                    }
                }
                if (gn < DIM) {
                    atomicAdd(&s_sum[lcol], ps);
                    atomicAdd(&s_sq[lcol], pq);
                }
            }
        }
        __syncthreads();
        // coalesced readback: 64 rows x 32 chunks of 4 fp16 (8B); DIM=300 is 4-aligned
#pragma unroll
        for (int it = 0; it < 8; it++) {
            int idx = tid + it * 256;
            int row = idx >> 5, ch = idx & 31;
            int gm = m0 + 64 * half + row, gcol = n0 + ch * 4;
            if (gm < N_NODES && gcol < DIM) {
                *(uint2*)(hout + (size_t)gm * DIM + gcol) =
                    *(const uint2*)(smem + row * CT_STRIDE + ch * 4);
            }
        }
        __syncthreads();
    }

    if (tid < 128) {
        int gn = n0 + tid;
        if (gn < DIM) {
            atomicAdd(&csum[gn], s_sum[tid]);
            atomicAdd(&csq[gn], s_sq[tid]);
        }
    }
}

// ------- Final output: BN2 of last layer (inline stats), fp16 h -> fp32 out -----------
__global__ void bn_apply_out(const ushort* __restrict__ h, const float* __restrict__ sum2,
                             const float* __restrict__ sq2, const float* __restrict__ g,
                             const float* __restrict__ b, float* __restrict__ out) {
    int idx = blockIdx.x * blockDim.x + threadIdx.x;  // pair index
    const int PAIRS = DIM / 2;
    if (idx >= N_NODES * PAIRS) return;
    int p = idx % PAIRS;
    const float invN = 1.0f / (float)N_NODES;
    float2 s = *(const float2*)(sum2 + 2 * p);
    float2 q = *(const float2*)(sq2 + 2 * p);
    float2 gv = *(const float2*)(g + 2 * p);
    float2 bv = *(const float2*)(b + 2 * p);
    float m0 = s.x * invN, m1 = s.y * invN;
    float sc0 = gv.x * rsqrtf(q.x * invN - m0 * m0 + 1e-5f);
    float sc1 = gv.y * rsqrtf(q.y * invN - m1 * m1 + 1e-5f);
    float sh0 = bv.x - m0 * sc0, sh1 = bv.y - m1 * sc1;
    uint u = ((const uint*)h)[idx];
    float2 o;
    o.x = h2f((ushort)(u & 0xffffu)) * sc0 + sh0;
    o.y = h2f((ushort)(u >> 16)) * sc1 + sh1;
    *(float2*)(out + 2 * idx) = o;
}

extern "C" void kernel_launch(void* const* d_in, const int* in_sizes, int n_in,
                              void* d_out, int out_size, void* d_ws, size_t ws_size,
                              hipStream_t stream) {
    const int* x = (const int*)d_in[0];
    const int* ei = (const int*)d_in[1];
    const int* ea = (const int*)d_in[2];
    const float* atom_emb = (const float*)d_in[3];
    const float* bond_emb = (const float*)d_in[4];
    const float* eps = (const float*)d_in[5];
    const float* W1 = (const float*)d_in[6];
    const float* b1 = (const float*)d_in[7];
    const float* g1 = (const float*)d_in[8];
    const float* be1 = (const float*)d_in[9];
    const float* W2 = (const float*)d_in[10];
    const float* b2 = (const float*)d_in[11];
    const float* gamma = (const float*)d_in[12];
    const float* beta = (const float*)d_in[13];
    float* out = (float*)d_out;

    float* ws = (float*)d_ws;
    ushort* h    = (ushort*)ws;                          // N*DIM us = 7,500,000 f
    ushort* A1h  = (ushort*)(ws + 7500000);              // MPAD*KP1 us = 8,007,680 f
    ushort* yh   = (ushort*)(ws + 15507680);             // MPAD*KP2 us = 15,214,592 f
    ushort* Wt1  = (ushort*)(ws + 30722272);             // NP1*KP1 us = 102,400 f
    ushort* Wt2  = (ushort*)(ws + 30824672);             // NP2*KP2 us = 116,736 f
    ushort* bondh = (ushort*)(ws + 30941408);            // 48*DIM us = 7,200 f
    float* stats = ws + 30948608;                        // 1,800 f used
    ushort* t1h  = (ushort*)(ws + 30952208);             // KP2 us = 304 f
    int* rowstart = (int*)(ws + 30952512);               // N+1
    int* deg      = rowstart + 50001;
    int* cursor   = deg + 50000;
    int2* epack   = (int2*)(cursor + 50000 + 1);         // align to 8B
    int* bsum     = (int*)(epack + 250000);              // SCAN_BLOCKS

    // ht (pre-transformed h, 15M us = 7.5M f) overlays the yh region: written at
    // layer top (yh of prev layer already consumed by gemm2), consumed by agg_combine
    // BEFORE gemm1 overwrites yh. Provably disjoint lifetimes; zero extra workspace.
    ushort* ht = yh;

    float* sum1 = stats;
    float* sq1  = stats + 600;
    float* sum2 = stats + 1200;
    float* sq2  = stats + 1500;

    const int PAIRS_N = N_NODES * (DIM / 2);

    // CSR build (once; edge_index is layer-invariant)
    hipMemsetAsync(deg, 0, 50000 * sizeof(int), stream);
    deg_count<<<(N_EDGES + 255) / 256, 256, 0, stream>>>(ei, deg);
    block_sums<<<SCAN_BLOCKS, 256, 0, stream>>>(deg, bsum);
    scan_bsums<<<1, 256, 0, stream>>>(bsum);
    write_rowstart<<<SCAN_BLOCKS, 256, 0, stream>>>(deg, bsum, rowstart, cursor);
    csr_fill<<<(N_EDGES + 255) / 256, 256, 0, stream>>>(ei, ea, cursor, epack);

    atom_enc<<<(PAIRS_N + 255) / 256, 256, 0, stream>>>(x, atom_emb, h);

    const int NBWT = 48 * (DIM / 2) + KP1 * NP1;  // fused bond+wt grid

    for (int l = 0; l < NL; ++l) {
        // pre-transform h with PREVIOUS layer's BN2 stats (before memset clears them)
        if (l > 0)
            bn_relu_h<<<(PAIRS_N + 255) / 256, 256, 0, stream>>>(
                h, sum2, sq2, gamma + (size_t)(l - 1) * DIM, beta + (size_t)(l - 1) * DIM, ht);

        hipMemsetAsync(stats, 0, 1800 * sizeof(float), stream);

        bond_wt<<<(NBWT + 255) / 256, 256, 0, stream>>>(
            bond_emb + (size_t)l * 3 * 16 * DIM, bondh, W1 + (size_t)l * DIM * DIM2, Wt1);

        agg_combine<<<(MPAD + 3) / 4, 256, 0, stream>>>(rowstart, epack, bondh,
                                                        (l == 0) ? h : ht, eps, l, A1h);

        gemm_mfma<<<(MPAD / 128) * (NP1 / 128), 256, 0, stream>>>(
            A1h, Wt1, b1 + l * DIM2, yh, N_NODES, KP1, DIM2, KP2, NP1 / 128, sum1, sq1);

        wt_conv2_bn1<<<(KP2 * NP2 + 255) / 256, 256, 0, stream>>>(
            W2 + (size_t)l * DIM2 * DIM, sum1, sq1, g1 + l * DIM2, be1 + l * DIM2, Wt2, t1h);

        gemm2_fused<<<(MPAD / 128) * (NP2 / 128), 256, 0, stream>>>(
            yh, Wt2, t1h, b2 + l * DIM, h, sum2, sq2);
    }

    // final output: BN2 of last layer (inline stats), no ReLU
    bn_apply_out<<<(PAIRS_N + 255) / 256, 256, 0, stream>>>(
        h, sum2, sq2, gamma + (size_t)(NL - 1) * DIM, beta + (size_t)(NL - 1) * DIM, out);
}

// Round 12
// 1076.907 us; speedup vs baseline: 1.0307x; 1.0307x over previous
//
#include <hip/hip_runtime.h>

#define N_NODES 50000
#define N_EDGES 250000
#define DIM 300
#define DIM2 600
#define NL 5
#define MPAD 50048      // 391 * 128
#define KP1 320         // DIM padded to mult of 32
#define KP2 608         // DIM2 padded to mult of 32
#define NP1 640         // DIM2 padded to mult of 128
#define NP2 384         // DIM padded to mult of 128
#define SCAN_BLOCKS 196 // ceil(N_NODES / 256)
#define CT_STRIDE 136   // 128 + 8 pad: breaks epilogue LDS write conflicts

typedef __attribute__((ext_vector_type(8))) _Float16 half8;
typedef __attribute__((ext_vector_type(2))) _Float16 half2v;
typedef __attribute__((ext_vector_type(8))) short short8;
typedef __attribute__((ext_vector_type(4))) float f32x4;
typedef unsigned short ushort;
typedef unsigned int uint;

#define AS1 __attribute__((address_space(1)))
#define AS3 __attribute__((address_space(3)))

// raw barrier with compiler memory fences: does NOT force a vmcnt drain
#define BARRIER() do { \
    asm volatile("" ::: "memory"); \
    __builtin_amdgcn_s_barrier(); \
    asm volatile("" ::: "memory"); \
} while (0)

static __device__ __forceinline__ ushort f2h(float f) {
    _Float16 h = (_Float16)f;
    return __builtin_bit_cast(ushort, h);
}
static __device__ __forceinline__ float h2f(ushort s) {
    return (float)__builtin_bit_cast(_Float16, s);
}
static __device__ __forceinline__ uint pk2(float a, float b) {
    return (uint)f2h(a) | ((uint)f2h(b) << 16);
}
static __device__ __forceinline__ half2v u2h2(uint u) {
    return __builtin_bit_cast(half2v, u);
}

// bijective XCD-contiguous remap (m204)
static __device__ __forceinline__ int xcd_swizzle(int o, int nwg) {
    int q = nwg >> 3, r = nwg & 7;
    int xcd = o & 7, idx = o >> 3;
    return (xcd < r ? xcd * (q + 1) : r * (q + 1) + (xcd - r) * q) + idx;
}

// ---------------- Atom encoder -> h fp16 ----------------
__global__ void atom_enc(const int* __restrict__ x, const float* __restrict__ emb,
                         ushort* __restrict__ h) {
    int idx = blockIdx.x * blockDim.x + threadIdx.x;  // pair index
    const int PAIRS = DIM / 2;  // 150
    if (idx >= N_NODES * PAIRS) return;
    int n = idx / PAIRS, p = idx - n * PAIRS;
    const int* xr = x + n * 9;
    float s0 = 0.f, s1 = 0.f;
#pragma unroll
    for (int i = 0; i < 9; i++) {
        const float2 v = *(const float2*)(emb + (size_t)(i * 128 + xr[i]) * DIM + 2 * p);
        s0 += v.x; s1 += v.y;
    }
    ((uint*)h)[idx] = pk2(s0, s1);
}

// ---------------- CSR build (once per launch; edge_index is layer-invariant) ----------
__global__ void deg_count(const int* __restrict__ ei, int* __restrict__ deg) {
    int e = blockIdx.x * blockDim.x + threadIdx.x;
    if (e < N_EDGES) atomicAdd(&deg[ei[N_EDGES + e]], 1);
}

__global__ void block_sums(const int* __restrict__ deg, int* __restrict__ bsum) {
    __shared__ int red[256];
    int tid = threadIdx.x;
    int node = blockIdx.x * 256 + tid;
    red[tid] = (node < N_NODES) ? deg[node] : 0;
    __syncthreads();
    for (int off = 128; off > 0; off >>= 1) {
        if (tid < off) red[tid] += red[tid + off];
        __syncthreads();
    }
    if (tid == 0) bsum[blockIdx.x] = red[0];
}

__global__ void scan_bsums(int* __restrict__ bsum) {
    __shared__ int s[256];
    int tid = threadIdx.x;
    int orig = (tid < SCAN_BLOCKS) ? bsum[tid] : 0;
    s[tid] = orig;
    __syncthreads();
    for (int off = 1; off < 256; off <<= 1) {
        int v = (tid >= off) ? s[tid - off] : 0;
        __syncthreads();
        s[tid] += v;
        __syncthreads();
    }
    if (tid < SCAN_BLOCKS) bsum[tid] = s[tid] - orig;  // exclusive
}

__global__ void write_rowstart(const int* __restrict__ deg, const int* __restrict__ bsum,
                               int* __restrict__ rowstart, int* __restrict__ cursor) {
    __shared__ int s[256];
    int tid = threadIdx.x;
    int node = blockIdx.x * 256 + tid;
    int d = (node < N_NODES) ? deg[node] : 0;
    s[tid] = d;
    __syncthreads();
    for (int off = 1; off < 256; off <<= 1) {
        int v = (tid >= off) ? s[tid - off] : 0;
        __syncthreads();
        s[tid] += v;
        __syncthreads();
    }
    int excl = s[tid] - d + bsum[blockIdx.x];
    if (node < N_NODES) {
        rowstart[node] = excl;
        cursor[node] = excl;
    }
    if (blockIdx.x == 0 && tid == 0) rowstart[N_NODES] = N_EDGES;
}

// fill CSR with pre-packed edge payload: (src, a0|a1<<8|a2<<16)
__global__ void csr_fill(const int* __restrict__ ei, const int* __restrict__ ea,
                         int* __restrict__ cursor, int2* __restrict__ epack) {
    int e = blockIdx.x * blockDim.x + threadIdx.x;
    if (e < N_EDGES) {
        int d = ei[N_EDGES + e];
        int slot = atomicAdd(&cursor[d], 1);
        int attr = ea[3 * e] | (ea[3 * e + 1] << 8) | (ea[3 * e + 2] << 16);
        epack[slot] = make_int2(ei[e], attr);
    }
}

// -------- fused per-layer: bond table fp32->fp16 + W1 transpose (indep of stats) ------
__global__ void bond_wt(const float* __restrict__ bond, ushort* __restrict__ bondh,
                        const float* __restrict__ W, ushort* __restrict__ Wt) {
    int idx = blockIdx.x * blockDim.x + threadIdx.x;
    const int NB = 48 * (DIM / 2);  // 7200 pair elems
    if (idx < NB) {
        float2 v = *(const float2*)(bond + 2 * idx);
        ((uint*)bondh)[idx] = pk2(v.x, v.y);
        return;
    }
    idx -= NB;
    if (idx >= KP1 * NP1) return;
    int k = idx / NP1, n = idx - k * NP1;
    ushort v = 0;
    if (k < DIM && n < DIM2) v = f2h(W[(size_t)k * DIM2 + n]);
    Wt[(size_t)n * KP1 + k] = v;
}

// -------- pre-transform h once per layer: ht = relu(bn2(h)) with inline stats ---------
__global__ void bn_relu_h(const ushort* __restrict__ h, const float* __restrict__ sum2,
                          const float* __restrict__ sq2, const float* __restrict__ g,
                          const float* __restrict__ b, ushort* __restrict__ ht) {
    int idx = blockIdx.x * blockDim.x + threadIdx.x;  // pair index
    const int PAIRS = DIM / 2;
    if (idx >= N_NODES * PAIRS) return;
    int p = idx % PAIRS;
    const float invN = 1.0f / (float)N_NODES;
    float2 s = *(const float2*)(sum2 + 2 * p);
    float2 q = *(const float2*)(sq2 + 2 * p);
    float2 gv = *(const float2*)(g + 2 * p);
    float2 bv = *(const float2*)(b + 2 * p);
    float m0 = s.x * invN, m1 = s.y * invN;
    float sc0 = gv.x * rsqrtf(q.x * invN - m0 * m0 + 1e-5f);
    float sc1 = gv.y * rsqrtf(q.y * invN - m1 * m1 + 1e-5f);
    float sh0 = bv.x - m0 * sc0, sh1 = bv.y - m1 * sc1;
    uint u = ((const uint*)h)[idx];
    float v0 = fmaxf(h2f((ushort)(u & 0xffffu)) * sc0 + sh0, 0.f);
    float v1 = fmaxf(h2f((ushort)(u >> 16)) * sc1 + sh1, 0.f);
    ((uint*)ht)[idx] = pk2(v0, v1);
}

// ------- gather-aggregate + GIN combine on PRE-TRANSFORMED ht + fp16 cast -------------
__launch_bounds__(256)
__global__ void agg_combine(const int* __restrict__ rowstart, const int2* __restrict__ epack,
                            const ushort* __restrict__ bondh, const ushort* __restrict__ ht,
                            const float* __restrict__ epsp, int layer,
                            ushort* __restrict__ A1) {
    int node = blockIdx.x * 4 + (threadIdx.x >> 6);
    int lane = threadIdx.x & 63;
    if (node >= MPAD) return;
    uint* row32 = (uint*)(A1 + (size_t)node * KP1);
    if (node >= N_NODES) {
        for (int i = lane; i < KP1 / 2; i += 64) row32[i] = 0;
        return;
    }
    const int PAIRS = DIM / 2;  // 150
    float epsv = 1.0f + epsp[layer];
    const uint* hd = (const uint*)(ht + (size_t)node * DIM);
    float ax[3], ay[3];
#pragma unroll
    for (int i = 0; i < 3; i++) {
        int p = lane + 64 * i;
        ax[i] = 0.f; ay[i] = 0.f;
        if (p < PAIRS) {
            uint u = hd[p];
            ax[i] = epsv * h2f((ushort)(u & 0xffffu));
            ay[i] = epsv * h2f((ushort)(u >> 16));
        }
    }

    auto edge_contrib = [&](int2 pk) {
        const uint* hs = (const uint*)(ht + (size_t)pk.x * DIM);
        int a0 = pk.y & 0xff, a1v = (pk.y >> 8) & 0xff, a2 = (pk.y >> 16) & 0xff;
        const uint* t0 = (const uint*)(bondh + a0 * DIM);
        const uint* t1 = (const uint*)(bondh + (16 + a1v) * DIM);
        const uint* t2 = (const uint*)(bondh + (32 + a2) * DIM);
        const half2v z = {};
#pragma unroll
        for (int i = 0; i < 3; i++) {
            int p = lane + 64 * i;
            if (p < PAIRS) {
                half2v m = u2h2(hs[p]) + u2h2(t0[p]) + u2h2(t1[p]) + u2h2(t2[p]);
                m = __builtin_elementwise_max(m, z);
                ax[i] += (float)m.x;
                ay[i] += (float)m.y;
            }
        }
    };

    int e0 = rowstart[node], e1 = rowstart[node + 1];
    int t = e0;
    for (; t + 1 < e1; t += 2) {
        int2 p0 = epack[t];
        int2 p1 = epack[t + 1];
        edge_contrib(p0);
        edge_contrib(p1);
    }
    if (t < e1) edge_contrib(epack[t]);

#pragma unroll
    for (int i = 0; i < 3; i++) {
        int p = lane + 64 * i;
        if (p < KP1 / 2) row32[p] = (p < PAIRS) ? pk2(ax[i], ay[i]) : 0u;
    }
}

// ------- W2 transpose with BN1 scale computed inline from stats; also emits t1h -------
__global__ void wt_conv2_bn1(const float* __restrict__ W, const float* __restrict__ sum1,
                             const float* __restrict__ sq1, const float* __restrict__ g1v,
                             const float* __restrict__ be1v, ushort* __restrict__ Wt,
                             ushort* __restrict__ th) {
    int idx = blockIdx.x * blockDim.x + threadIdx.x;
    const float invN = 1.0f / (float)N_NODES;
    if (idx < KP2) {  // t1h = shift1/scale1, zero pad past DIM2
        ushort tv = 0;
        if (idx < DIM2) {
            float mean = sum1[idx] * invN;
            float var = sq1[idx] * invN - mean * mean;
            float sc = g1v[idx] * rsqrtf(var + 1e-5f);
            tv = f2h(be1v[idx] / sc - mean);
        }
        th[idx] = tv;
    }
    if (idx >= KP2 * NP2) return;
    int k = idx / NP2, n = idx - k * NP2;
    ushort v = 0;
    if (k < DIM2 && n < DIM) {
        float mean = sum1[k] * invN;
        float var = sq1[k] * invN - mean * mean;
        float sc = g1v[k] * rsqrtf(var + 1e-5f);
        v = f2h(sc * W[(size_t)k * DIM + n]);
    }
    Wt[(size_t)n * KP2 + k] = v;
}

// ---------------- GEMM1: yh = A1 @ Wt1^T + b1, fp16 out + BN stats --------------------
// TLP experiment: 512 threads = 8 waves (2x4 wave grid, wave-tile 64x32, acc[4][2]=32
// acc regs). Total regs ~<=112 -> 16 waves/CU (vs 144 regs / 8 waves before). Schedule
// is R4's proven depth-2 counted-vmcnt pipeline, unchanged (stage = 2 glds/wave now,
// so counted waits are vmcnt(2)). Tiles/LDS/traffic per block identical.
__launch_bounds__(512)
__global__ void gemm_mfma(const ushort* __restrict__ A, const ushort* __restrict__ Wt,
                          const float* __restrict__ bias, ushort* __restrict__ Cout,
                          int M, int KP, int Nc, int strideC, int ntiles,
                          float* __restrict__ csum, float* __restrict__ csq) {
    __shared__ ushort smem[16384];  // 32 KB: As0@0 Bs0@4096 As1@8192 Bs1@12288 (elem offs)
    __shared__ float s_sum[128], s_sq[128];

    int tid = threadIdx.x;
    int w = tid >> 6, lane = tid & 63;   // w 0..7
    int quad = lane >> 4, lr = lane & 15;
    int wm = w >> 2, wn = w & 3;         // 2 x 4 wave grid
    int wg = xcd_swizzle(blockIdx.x, gridDim.x);
    int m0 = (wg / ntiles) * 128;
    int n0 = (wg % ntiles) * 128;

    if (tid < 128) { s_sum[tid] = 0.f; s_sq[tid] = 0.f; }

    const int kchunk = ((lane & 3) ^ ((lane >> 3) & 3)) * 8;
    const int grow = lane >> 2;
    const ushort* Abase = A + (size_t)m0 * KP + kchunk;
    const ushort* Bbase = Wt + (size_t)n0 * KP + kchunk;
    const int xq = (quad ^ ((lr >> 1) & 3)) * 8;  // matching swizzled read slot

    auto stage = [&](int k0, int buf) {  // 2 glds per wave (1 A chunk + 1 B chunk)
        ushort* dA = smem + buf * 8192;
        int c = w;  // 8 chunks of 16 rows, one per wave
        __builtin_amdgcn_global_load_lds((const AS1 void*)(Abase + (size_t)(16 * c + grow) * KP + k0),
                                         (AS3 void*)(dA + c * 512), 16, 0, 0);
        __builtin_amdgcn_global_load_lds((const AS1 void*)(Bbase + (size_t)(16 * c + grow) * KP + k0),
                                         (AS3 void*)(dA + 4096 + c * 512), 16, 0, 0);
    };

    f32x4 acc[4][2] = {};
    const int nk = KP >> 5;  // 10

    stage(0, 0);
    stage(32, 1);
    asm volatile("s_waitcnt vmcnt(2)" ::: "memory");  // tile 0 landed; tile 1 in flight
    BARRIER();

    for (int t = 0; t < nk; ++t) {
        const ushort* As = smem + (t & 1) * 8192;
        const ushort* Bs = As + 4096;
        half8 a[4], b[2];
#pragma unroll
        for (int mf = 0; mf < 4; mf++)
            a[mf] = __builtin_bit_cast(half8, *(const short8*)(As + (64 * wm + 16 * mf + lr) * 32 + xq));
#pragma unroll
        for (int nf = 0; nf < 2; nf++)
            b[nf] = __builtin_bit_cast(half8, *(const short8*)(Bs + (32 * wn + 16 * nf + lr) * 32 + xq));
        asm volatile("s_waitcnt lgkmcnt(0)" ::: "memory");  // reads complete -> buf free
        BARRIER();

        if (t + 2 < nk) stage((t + 2) << 5, t & 1);  // overwrite just-freed buffer

        __builtin_amdgcn_s_setprio(1);
#pragma unroll
        for (int mf = 0; mf < 4; mf++)
#pragma unroll
            for (int nf = 0; nf < 2; nf++)
                acc[mf][nf] = __builtin_amdgcn_mfma_f32_16x16x32_f16(a[mf], b[nf], acc[mf][nf], 0, 0, 0);
        __builtin_amdgcn_s_setprio(0);

        if (t + 2 < nk)       { asm volatile("s_waitcnt vmcnt(2)" ::: "memory"); }  // t+1 landed
        else if (t + 1 < nk)  { asm volatile("s_waitcnt vmcnt(0)" ::: "memory"); }  // tail drain
        BARRIER();
    }

    // Epilogue: stats from regs + two 64-row half-tiles through LDS (reuses staging smem)
#pragma unroll
    for (int half = 0; half < 2; half++) {
        if (wm == half) {
#pragma unroll
            for (int nf = 0; nf < 2; nf++) {
                int lcol = 32 * wn + 16 * nf + lr;
                int gn = n0 + lcol;
                float bv = (gn < Nc) ? bias[gn] : 0.f;
                float ps = 0.f, pq = 0.f;
#pragma unroll
                for (int mf = 0; mf < 4; mf++) {
#pragma unroll
                    for (int r = 0; r < 4; r++) {
                        int lrow = 16 * mf + quad * 4 + r;  // 0..63 within half
                        float v = acc[mf][nf][r] + bv;
                        smem[lrow * CT_STRIDE + lcol] = f2h(v);
                        if (m0 + 64 * half + lrow < M && gn < Nc) { ps += v; pq += v * v; }
                    }
                }
                if (gn < Nc) {
                    atomicAdd(&s_sum[lcol], ps);
                    atomicAdd(&s_sq[lcol], pq);
                }
            }
        }
        __syncthreads();
        // coalesced readback: 64 rows x 16 chunks of 8 fp16 (16B); 512 thr -> 2 iters
#pragma unroll
        for (int it = 0; it < 2; it++) {
            int idx = tid + it * 512;
            int row = idx >> 4, ch = idx & 15;
            int gcol = n0 + ch * 8;
            if (gcol < strideC) {
                *(short8*)(Cout + (size_t)(m0 + 64 * half + row) * strideC + gcol) =
                    *(const short8*)(smem + row * CT_STRIDE + ch * 8);
            }
        }
        __syncthreads();
    }

    if (tid < 128) {
        int gn = n0 + tid;
        if (gn < Nc) {
            atomicAdd(&csum[gn], s_sum[tid]);
            atomicAdd(&csq[gn], s_sq[tid]);
        }
    }
}

// ------- GEMM2: h = max(yh + t1h, 0) @ Wt2^T + b2 -- transform ON THE FRAGMENT --------
// Same TLP experiment on the R7/R10 3-buf 1-barrier structure: 8 waves, acc[4][2],
// stage = 2 glds/wave, counted vmcnt(2).
__launch_bounds__(512)
__global__ void gemm2_fused(const ushort* __restrict__ yh, const ushort* __restrict__ Wt,
                            const ushort* __restrict__ t1h, const float* __restrict__ bias,
                            ushort* __restrict__ hout,
                            float* __restrict__ csum, float* __restrict__ csq) {
    __shared__ ushort smem[24576];
    __shared__ ushort s_t[KP2];
    __shared__ float s_sum[128], s_sq[128];

    int tid = threadIdx.x;
    int w = tid >> 6, lane = tid & 63;   // w 0..7
    int quad = lane >> 4, lr = lane & 15;
    int wm = w >> 2, wn = w & 3;         // 2 x 4 wave grid
    int wg = xcd_swizzle(blockIdx.x, gridDim.x);
    int m0 = (wg / 3) * 128;
    int n0 = (wg % 3) * 128;

    if (tid < 128) { s_sum[tid] = 0.f; s_sq[tid] = 0.f; }

    const int kchunk = ((lane & 3) ^ ((lane >> 3) & 3)) * 8;
    const int grow = lane >> 2;
    const ushort* Abase = yh + (size_t)m0 * KP2 + kchunk;
    const ushort* Bbase = Wt + (size_t)n0 * KP2 + kchunk;
    const int xq = (quad ^ ((lr >> 1) & 3)) * 8;

    auto stage = [&](int k0, int buf) {  // 2 glds per wave (1 A chunk + 1 B chunk)
        ushort* dA = smem + buf * 4096;
        ushort* dB = smem + 12288 + buf * 4096;
        int c = w;
        __builtin_amdgcn_global_load_lds((const AS1 void*)(Abase + (size_t)(16 * c + grow) * KP2 + k0),
                                         (AS3 void*)(dA + c * 512), 16, 0, 0);
        __builtin_amdgcn_global_load_lds((const AS1 void*)(Bbase + (size_t)(16 * c + grow) * KP2 + k0),
                                         (AS3 void*)(dB + c * 512), 16, 0, 0);
    };

    // prologue: s_t (t1h, zero-padded to KP2), then tiles 0,1
    for (int i = tid; i < KP2 / 2; i += 512) ((uint*)s_t)[i] = ((const uint*)t1h)[i];
    asm volatile("s_waitcnt vmcnt(0) lgkmcnt(0)" ::: "memory");  // drain before counting
    stage(0, 0);
    stage(32, 1);
    asm volatile("s_waitcnt vmcnt(2)" ::: "memory");  // tile 0 landed (this wave)
    BARRIER();                                        // all waves; s_t visible

    f32x4 acc[4][2] = {};
    const int nk = KP2 >> 5;  // 19

    int cur = 0;
    for (int t = 0; t < nk; ++t) {
        int s2 = cur + 2; if (s2 >= 3) s2 -= 3;
        if (t + 2 < nk) stage((t + 2) << 5, s2);

        const ushort* As = smem + cur * 4096;
        const ushort* Bs = smem + 12288 + cur * 4096;
        half8 a[4], b[2];
        half8 t8 = *(const half8*)(s_t + (t << 5) + quad * 8);  // broadcast within quad
#pragma unroll
        for (int mf = 0; mf < 4; mf++)
            a[mf] = __builtin_bit_cast(half8, *(const short8*)(As + (64 * wm + 16 * mf + lr) * 32 + xq));
#pragma unroll
        for (int nf = 0; nf < 2; nf++)
            b[nf] = __builtin_bit_cast(half8, *(const short8*)(Bs + (32 * wn + 16 * nf + lr) * 32 + xq));
        asm volatile("s_waitcnt lgkmcnt(0)" ::: "memory");

        __builtin_amdgcn_s_setprio(1);
        {
            half8 z = {};
#pragma unroll
            for (int mf = 0; mf < 4; mf++)
                a[mf] = __builtin_elementwise_max(a[mf] + t8, z);  // BN1 bias + ReLU
        }
#pragma unroll
        for (int mf = 0; mf < 4; mf++)
#pragma unroll
            for (int nf = 0; nf < 2; nf++)
                acc[mf][nf] = __builtin_amdgcn_mfma_f32_16x16x32_f16(a[mf], b[nf], acc[mf][nf], 0, 0, 0);
        __builtin_amdgcn_s_setprio(0);

        if (t + 2 < nk)       { asm volatile("s_waitcnt vmcnt(2)" ::: "memory"); }
        else if (t + 1 < nk)  { asm volatile("s_waitcnt vmcnt(0)" ::: "memory"); }
        BARRIER();

        cur = (cur + 1 == 3) ? 0 : cur + 1;
    }

    // Epilogue: stats from regs + two 64-row half-tiles through LDS
#pragma unroll
    for (int half = 0; half < 2; half++) {
        if (wm == half) {
#pragma unroll
            for (int nf = 0; nf < 2; nf++) {
                int lcol = 32 * wn + 16 * nf + lr;
                int gn = n0 + lcol;
                float bv = (gn < DIM) ? bias[gn] : 0.f;
                float ps = 0.f, pq = 0.f;
#pragma unroll
                for (int mf = 0; mf < 4; mf++) {
#pragma unroll
                    for (int r = 0; r < 4; r++) {
                        int lrow = 16 * mf + quad * 4 + r;  // 0..63 within half
                        float v = acc[mf][nf][r] + bv;
                        smem[lrow * CT_STRIDE + lcol] = f2h(v);
                        if (m0 + 64 * half + lrow < N_NODES && gn < DIM) { ps += v; pq += v * v; }
                    }
                }
                if (gn < DIM) {
                    atomicAdd(&s_sum[lcol], ps);
                    atomicAdd(&s_sq[lcol], pq);
                }
            }
        }
        __syncthreads();
        // coalesced readback: 64 rows x 32 chunks of 4 fp16 (8B); 512 thr -> 4 iters
#pragma unroll
        for (int it = 0; it < 4; it++) {
            int idx = tid + it * 512;
            int row = idx >> 5, ch = idx & 31;
            int gm = m0 + 64 * half + row, gcol = n0 + ch * 4;
            if (gm < N_NODES && gcol < DIM) {
                *(uint2*)(hout + (size_t)gm * DIM + gcol) =
                    *(const uint2*)(smem + row * CT_STRIDE + ch * 4);
            }
        }
        __syncthreads();
    }

    if (tid < 128) {
        int gn = n0 + tid;
        if (gn < DIM) {
            atomicAdd(&csum[gn], s_sum[tid]);
            atomicAdd(&csq[gn], s_sq[tid]);
        }
    }
}

// ------- Final output: BN2 of last layer (inline stats), fp16 h -> fp32 out -----------
__global__ void bn_apply_out(const ushort* __restrict__ h, const float* __restrict__ sum2,
                             const float* __restrict__ sq2, const float* __restrict__ g,
                             const float* __restrict__ b, float* __restrict__ out) {
    int idx = blockIdx.x * blockDim.x + threadIdx.x;  // pair index
    const int PAIRS = DIM / 2;
    if (idx >= N_NODES * PAIRS) return;
    int p = idx % PAIRS;
    const float invN = 1.0f / (float)N_NODES;
    float2 s = *(const float2*)(sum2 + 2 * p);
    float2 q = *(const float2*)(sq2 + 2 * p);
    float2 gv = *(const float2*)(g + 2 * p);
    float2 bv = *(const float2*)(b + 2 * p);
    float m0 = s.x * invN, m1 = s.y * invN;
    float sc0 = gv.x * rsqrtf(q.x * invN - m0 * m0 + 1e-5f);
    float sc1 = gv.y * rsqrtf(q.y * invN - m1 * m1 + 1e-5f);
    float sh0 = bv.x - m0 * sc0, sh1 = bv.y - m1 * sc1;
    uint u = ((const uint*)h)[idx];
    float2 o;
    o.x = h2f((ushort)(u & 0xffffu)) * sc0 + sh0;
    o.y = h2f((ushort)(u >> 16)) * sc1 + sh1;
    *(float2*)(out + 2 * idx) = o;
}

extern "C" void kernel_launch(void* const* d_in, const int* in_sizes, int n_in,
                              void* d_out, int out_size, void* d_ws, size_t ws_size,
                              hipStream_t stream) {
    const int* x = (const int*)d_in[0];
    const int* ei = (const int*)d_in[1];
    const int* ea = (const int*)d_in[2];
    const float* atom_emb = (const float*)d_in[3];
    const float* bond_emb = (const float*)d_in[4];
    const float* eps = (const float*)d_in[5];
    const float* W1 = (const float*)d_in[6];
    const float* b1 = (const float*)d_in[7];
    const float* g1 = (const float*)d_in[8];
    const float* be1 = (const float*)d_in[9];
    const float* W2 = (const float*)d_in[10];
    const float* b2 = (const float*)d_in[11];
    const float* gamma = (const float*)d_in[12];
    const float* beta = (const float*)d_in[13];
    float* out = (float*)d_out;

    float* ws = (float*)d_ws;
    ushort* h    = (ushort*)ws;                          // N*DIM us = 7,500,000 f
    ushort* A1h  = (ushort*)(ws + 7500000);              // MPAD*KP1 us = 8,007,680 f
    ushort* yh   = (ushort*)(ws + 15507680);             // MPAD*KP2 us = 15,214,592 f
    ushort* Wt1  = (ushort*)(ws + 30722272);             // NP1*KP1 us = 102,400 f
    ushort* Wt2  = (ushort*)(ws + 30824672);             // NP2*KP2 us = 116,736 f
    ushort* bondh = (ushort*)(ws + 30941408);            // 48*DIM us = 7,200 f
    float* stats = ws + 30948608;                        // 1,800 f used
    ushort* t1h  = (ushort*)(ws + 30952208);             // KP2 us = 304 f
    int* rowstart = (int*)(ws + 30952512);               // N+1
    int* deg      = rowstart + 50001;
    int* cursor   = deg + 50000;
    int2* epack   = (int2*)(cursor + 50000 + 1);         // align to 8B
    int* bsum     = (int*)(epack + 250000);              // SCAN_BLOCKS

    // ht (pre-transformed h) overlays the yh region: written at layer top (prev yh
    // consumed), consumed by agg_combine BEFORE gemm1 overwrites yh. Disjoint lifetimes.
    ushort* ht = yh;

    float* sum1 = stats;
    float* sq1  = stats + 600;
    float* sum2 = stats + 1200;
    float* sq2  = stats + 1500;

    const int PAIRS_N = N_NODES * (DIM / 2);

    // CSR build (once; edge_index is layer-invariant)
    hipMemsetAsync(deg, 0, 50000 * sizeof(int), stream);
    deg_count<<<(N_EDGES + 255) / 256, 256, 0, stream>>>(ei, deg);
    block_sums<<<SCAN_BLOCKS, 256, 0, stream>>>(deg, bsum);
    scan_bsums<<<1, 256, 0, stream>>>(bsum);
    write_rowstart<<<SCAN_BLOCKS, 256, 0, stream>>>(deg, bsum, rowstart, cursor);
    csr_fill<<<(N_EDGES + 255) / 256, 256, 0, stream>>>(ei, ea, cursor, epack);

    atom_enc<<<(PAIRS_N + 255) / 256, 256, 0, stream>>>(x, atom_emb, h);

    const int NBWT = 48 * (DIM / 2) + KP1 * NP1;  // fused bond+wt grid

    for (int l = 0; l < NL; ++l) {
        // pre-transform h with PREVIOUS layer's BN2 stats (before memset clears them)
        if (l > 0)
            bn_relu_h<<<(PAIRS_N + 255) / 256, 256, 0, stream>>>(
                h, sum2, sq2, gamma + (size_t)(l - 1) * DIM, beta + (size_t)(l - 1) * DIM, ht);

        hipMemsetAsync(stats, 0, 1800 * sizeof(float), stream);

        bond_wt<<<(NBWT + 255) / 256, 256, 0, stream>>>(
            bond_emb + (size_t)l * 3 * 16 * DIM, bondh, W1 + (size_t)l * DIM * DIM2, Wt1);

        agg_combine<<<(MPAD + 3) / 4, 256, 0, stream>>>(rowstart, epack, bondh,
                                                        (l == 0) ? h : ht, eps, l, A1h);

        gemm_mfma<<<(MPAD / 128) * (NP1 / 128), 512, 0, stream>>>(
            A1h, Wt1, b1 + l * DIM2, yh, N_NODES, KP1, DIM2, KP2, NP1 / 128, sum1, sq1);

        wt_conv2_bn1<<<(KP2 * NP2 + 255) / 256, 256, 0, stream>>>(
            W2 + (size_t)l * DIM2 * DIM, sum1, sq1, g1 + l * DIM2, be1 + l * DIM2, Wt2, t1h);

        gemm2_fused<<<(MPAD / 128) * (NP2 / 128), 512, 0, stream>>>(
            yh, Wt2, t1h, b2 + l * DIM, h, sum2, sq2);
    }

    // final output: BN2 of last layer (inline stats), no ReLU
    bn_apply_out<<<(PAIRS_N + 255) / 256, 256, 0, stream>>>(
        h, sum2, sq2, gamma + (size_t)(NL - 1) * DIM, beta + (size_t)(NL - 1) * DIM, out);
}